// Round 18
// baseline (824.455 us; speedup 1.0000x reference)
//
#include <hip/hip_runtime.h>

// DSDMSR_x8: 13-unit SRCNN cascade, fp32 I/O, bf16 MFMA compute.
// Per 12x12 output tile; R17: 512 thr / 8 waves, SAME LDS -> 3 blocks/CU
// = 24 waves/CU (was 12). RULES: (r8) disjoint acc lifetimes; (r11)
// compile-time reg indices; (r12) never cap occupancy below demand.
// R1 (verified r4, 994->847us): operands swapped (weights=A, pixels=B).
// R5 (verified r11, 847->639us): phase-2 n fused; A-frag read once.
// R12 (r13 NULL, kept): phase-1 gather k-permute.
// R14 (verified r16, 637->626us): dx0..3 folded into k (broadcast B-reads);
// conflicts -31% but only -1.4% time -> conflicts OFF critical path.
// R17 (theory: latency-bound at 12 waves/CU, no pipe >50%): 8-wave blocks.
//   phase 1: single m-pass, m = wv + im*8 (8x4 >= 25 tiles; 2-subset loop
//            deleted). Each (m,n) computed by exactly one wave, same k-order.
//   phase 2: wave = (wp = wv&3 row-group, nh = wv>>2 co-half). Per-wave
//            MFMA 400->200, weight loads 110->55 (block L2 traffic FLAT).
//            Per-accumulator (c8 asc, rel asc) order unchanged.
//   phase 3: mt = wv + 8*jm (wv0: 2 tiles, others 1).
// All phases preserve per-output summation order -> BIT-IDENTICAL output
// (absmax must be exactly 0.01220703).
// R17-resubmit (r17 broker timeout; unchanged).
// LDS 52928 B x3 = 159.7 KB -> 3 blocks/CU. Spill canary: WRITE_SIZE ~5 MB.

typedef unsigned short ushort_t;
typedef __attribute__((ext_vector_type(8))) short short8;   // 8 bf16
typedef __attribute__((ext_vector_type(4))) float f32x4;
typedef __attribute__((ext_vector_type(2))) unsigned int u32x2;

__device__ __forceinline__ float us2f(ushort_t u) { return __uint_as_float(((unsigned int)u) << 16); }
__device__ __forceinline__ ushort_t f2us(float f) {
    unsigned int x = __float_as_uint(f);
    return (ushort_t)((x + 0x7fffu + ((x >> 16) & 1u)) >> 16);
}
// pack two f32 -> two bf16 (RNE), one VOP3
__device__ __forceinline__ unsigned int pk_bf16(float lo, float hi) {
    unsigned int r;
    asm("v_cvt_pk_bf16_f32 %0, %1, %2" : "=v"(r) : "v"(lo), "v"(hi));
    return r;
}

#define MFMA16(a, b, c) __builtin_amdgcn_mfma_f32_16x16x32_bf16((a), (b), (c), 0, 0, 0)

// ---------------------------------------------------------------------------
// Weight prep (unchanged from r14):
//  w1t [u][kc3][cig4][ch64][8]  (tap = kc*32 + e*4 + cig, zero for tap>=81)
//  w2t: main [u][c8][dy][q=dx][co][e] then dx4 [u][c][dy][cig][co][e]
//  w3t [u][tap25][ci32]
// ---------------------------------------------------------------------------
__global__ __launch_bounds__(256) void prep_weights(
    const float* __restrict__ W1, const float* __restrict__ W2, const float* __restrict__ W3,
    ushort_t* __restrict__ w1t, ushort_t* __restrict__ w2t, ushort_t* __restrict__ w3t)
{
    int i = blockIdx.x * 256 + threadIdx.x;
    if (i < 13 * 3 * 4 * 64 * 8) {           // 79872
        int e = i & 7, ch = (i >> 3) & 63, cig = (i >> 9) & 3;
        int r = i >> 11;                     // u*3 + kc
        int kc = r % 3, u = r / 3;
        int tap = kc * 32 + e * 4 + cig;     // r12 k-permute
        w1t[i] = (tap < 81) ? f2us(W1[(u * 64 + ch) * 81 + tap]) : (ushort_t)0;
    }
    if (i < 532480) {                        // main: [u][c8][dy][q][co][e]
        int e = i & 7, co = (i >> 3) & 31, qq = (i >> 8) & 3;
        int b = i >> 10;                     // (u*8 + c8)*5 + dy
        int dy = b % 5, tt = b / 5;
        int c8 = tt % 8, u = tt / 8;
        int ci = c8 * 8 + e;
        int tap = dy * 5 + qq;               // dx = q
        w2t[i] = f2us(W2[((u * 32 + co) * 64 + ci) * 25 + tap]);
    }
    if (i < 133120) {                        // dx4: [u][c][dy][cig][co][e]
        int e = i & 7, co = (i >> 3) & 31, cig = (i >> 8) & 3;
        int b = i >> 10;                     // (u*2 + c)*5 + dy
        int dy = b % 5, s = b / 5;
        int c = s % 2, u = s / 2;
        int ci = c * 32 + cig * 8 + e;
        int tap = dy * 5 + 4;
        w2t[532480 + i] = f2us(W2[((u * 32 + co) * 64 + ci) * 25 + tap]);
    }
    if (i < 13 * 25 * 32) {                  // 10400
        int ci = i & 31, r = i >> 5;
        int tap = r % 25, u = r / 25;
        w3t[i] = f2us(W3[(u * 32 + ci) * 25 + tap]);
    }
}

// ---------------------------------------------------------------------------
__global__ __launch_bounds__(512, 2) void srcnn_mfma(
    const float* __restrict__ in, int H, int W,
    const ushort_t* __restrict__ w1t, const ushort_t* __restrict__ w2t,
    const ushort_t* __restrict__ w3t,
    const float* __restrict__ gB1, const float* __restrict__ gB2,
    const float* __restrict__ gB3,
    int unitBase, float* __restrict__ out, int s2)
{
    __shared__ __align__(16) char smem[52928];
    ushort_t* sH1  = (ushort_t*)smem;             // 8 planes x 3208 shorts = 51328 B
    ushort_t* sInU = (ushort_t*)(smem + 51328);   // 784 bf16 (conv1 only)
    ushort_t* sW3  = (ushort_t*)(smem + 51328);   // 800 u16 (after conv1)
    ushort_t* sH2  = (ushort_t*)smem;             // h2 4 x 2064 shorts (after conv2)

    const int t = threadIdx.x, lane = t & 63, wv = t >> 6;   // wv 0..7
    const int q = lane >> 4, l15 = lane & 15;
    const int wp = wv & 3, nh = wv >> 2;                     // phase-2 split
    const int z = blockIdx.z;
    const int k4 = (s2 == 2) ? (z >> 2) : 0;
    const int b  = (s2 == 2) ? (z & 3)  : z;
    const int unit = unitBase + k4;
    const int ppx = k4 & 1, ppy = k4 >> 1;
    const int ox0 = blockIdx.x * 12, oy0 = blockIdx.y * 12;
    const int outW = W * s2;
    const int outH = H * s2;
    const float* inb = in + (size_t)b * H * W;

    // r14 weight regions (bytes)
    const char* w2m_u = (const char*)w2t + (size_t)unit * 81920;
    const char* w2x_u = (const char*)w2t + 1064960 + (size_t)unit * 20480;

    // load a 5-frag weight set [dy] for this wave's co-half nh
    auto loadW5 = [&](short8* buf, const char* base, int blk) {
        const char* g = base + (size_t)blk * 10240 + q * 512 + nh * 256 + l15 * 16;
#pragma unroll
        for (int dy = 0; dy < 5; ++dy)
            buf[dy] = *(const short8*)(g + dy * 2048);
    };

    // stage input 28x28 (origin -8, zero-padded) as bf16
    for (int idx = t; idx < 784; idx += 512) {
        int y = idx / 28, x = idx - 28 * y;
        int gy = oy0 - 8 + y, gx = ox0 - 8 + x;
        sInU[idx] = (gy >= 0 && gy < H && gx >= 0 && gx < W)
                    ? f2us(inb[(size_t)gy * W + gx]) : (ushort_t)0;
    }
    __syncthreads();

    const ushort_t* w1u = w1t + (size_t)unit * (3 * 4 * 64 * 8);

    // ---- phase 1: conv1, fused ci (4 n-tiles), SINGLE m-pass over 8 waves ----
    f32x4 bias4[4];
#pragma unroll
    for (int n = 0; n < 4; ++n)
        bias4[n] = *(const f32x4*)&gB1[unit * 64 + n * 16 + q * 4];

    const int nim1 = (wv == 0) ? 4 : 3;      // m = wv + im*8 < 25
    {
        f32x4 acc1h[4][4];
#pragma unroll
        for (int i = 0; i < 4; ++i)
#pragma unroll
            for (int n = 0; n < 4; ++n) acc1h[i][n] = (f32x4){0.f, 0.f, 0.f, 0.f};

#pragma unroll 1
        for (int kc = 0; kc < 3; ++kc) {
            short8 bh[4];
#pragma unroll
            for (int n = 0; n < 4; ++n)
                bh[n] = *(const short8*)&w1u[((kc * 4 + q) * 64 + n * 16 + l15) * 8];
            int toff8[8];
#pragma unroll
            for (int j = 0; j < 8; ++j) {
                int T = kc * 32 + j * 4 + q;
                int ty = (T * 57) >> 9;
                int o  = ty * 28 + (T - 9 * ty);
                toff8[j] = (T < 81) ? o : 0;
            }
#pragma unroll
            for (int im = 0; im < 4; ++im) {
                if (im < nim1) {
                    int m = wv + im * 8;              // 0..24
                    int px = m * 16 + l15;            // 0..399 (20x20 h1 grid)
                    int py1 = (px * 205) >> 12;
                    int base = py1 * 28 + (px - 20 * py1);
                    union { short8 v; ushort_t u[8]; } a;
#pragma unroll
                    for (int j = 0; j < 8; ++j)
                        a.u[j] = sInU[base + toff8[j]];
#pragma unroll
                    for (int n = 0; n < 4; ++n)
                        acc1h[im][n] = MFMA16(bh[n], a.v, acc1h[im][n]);
                }
            }
        }

        // writeback: lane owns pixel px, channels n*16+q*4+{0..3}
#pragma unroll
        for (int im = 0; im < 4; ++im) {
            if (im < nim1) {
                int m = wv + im * 8;
                int px = m * 16 + l15;
                int py1 = (px * 205) >> 12;
                int px1 = px - 20 * py1;
                int gy = oy0 - 4 + py1, gx = ox0 - 4 + px1;
                bool ok = (gy >= 0 && gy < H && gx >= 0 && gx < W);
#pragma unroll
                for (int n = 0; n < 4; ++n) {
                    float v0 = fmaxf(acc1h[im][n][0] + bias4[n][0], 0.f);
                    float v1 = fmaxf(acc1h[im][n][1] + bias4[n][1], 0.f);
                    float v2 = fmaxf(acc1h[im][n][2] + bias4[n][2], 0.f);
                    float v3 = fmaxf(acc1h[im][n][3] + bias4[n][3], 0.f);
                    unsigned int w0 = pk_bf16(v0, v1);
                    unsigned int w1 = pk_bf16(v2, v3);
                    if (!ok) { w0 = 0u; w1 = 0u; }
                    *(u32x2*)&sH1[(n * 2 + (q >> 1)) * 3208 + px * 8 + (q & 1) * 4]
                        = (u32x2){w0, w1};
                }
            }
        }
    }
    __syncthreads();   // all h1 written; all sInU reads done

    // stage w3 into sInU region (dead); visible to conv3 via the post-h2 barrier
    {
        const ushort_t* w3u = w3t + unit * 800;
        for (int i = t; i < 800; i += 512) sW3[i] = w3u[i];
    }

    // ---- phase 2: conv2; wave = (wp row-group, nh co-half) ----
    // Main leg (dx 0..3 in k): per (c8, rel): ONE broadcast-friendly B-read.
    // dx4 leg: classic k=32ci. Per-accumulator order (c8 asc, rel asc) same
    // as r14 -> bit-identical.
    f32x4 acc2[4];
#pragma unroll
    for (int i = 0; i < 4; ++i) acc2[i] = (f32x4){0.f, 0.f, 0.f, 0.f};

    {
        short8 Wa[5], Wb[5];
        loadW5(Wa, w2m_u, 0);
#pragma unroll
        for (int c8 = 0; c8 < 8; ++c8) {
            const short8* cw = (c8 & 1) ? Wb : Wa;   // compile-time
            short8*       nw = (c8 & 1) ? Wa : Wb;
            if (c8 < 7) loadW5(nw, w2m_u, c8 + 1);
            else        loadW5(nw, w2x_u, 0);        // prefetch dx4 c=0
            const ushort_t* bpl = &sH1[c8 * 3208];
#pragma unroll
            for (int rel = 0; rel < 8; ++rel) {
                int row = wp * 4 + rel;
                short8 bf = *(const short8*)&bpl[(row * 20 + l15 + q) * 8];
                const int dylo = rel - 3 < 0 ? 0 : rel - 3;
                const int dyhi = rel < 4 ? rel : 4;
#pragma unroll
                for (int dy = 0; dy < 5; ++dy) {
                    if (dy >= dylo && dy <= dyhi) {
                        int im = rel - dy;
                        acc2[im] = MFMA16(cw[dy], bf, acc2[im]);
                    }
                }
            }
        }
        // dx4 leg: c=0 weights already prefetched above
#pragma unroll
        for (int c = 0; c < 2; ++c) {
            const short8* cw = (c & 1) ? Wb : Wa;
            short8*       nw = (c & 1) ? Wa : Wb;
            if (c == 0) loadW5(nw, w2x_u, 1);
            const ushort_t* base = &sH1[(c * 4 + q) * 3208];
#pragma unroll
            for (int rel = 0; rel < 8; ++rel) {
                int row = wp * 4 + rel;
                short8 bf = *(const short8*)&base[(row * 20 + l15 + 4) * 8];
                const int dylo = rel - 3 < 0 ? 0 : rel - 3;
                const int dyhi = rel < 4 ? rel : 4;
#pragma unroll
                for (int dy = 0; dy < 5; ++dy) {
                    if (dy >= dylo && dy <= dyhi) {
                        int im = rel - dy;
                        acc2[im] = MFMA16(cw[dy], bf, acc2[im]);
                    }
                }
            }
        }
    }
    __syncthreads();   // all sH1 reads done before h2 overwrites it

    // ---- h2 writeback: wave (wp, nh); lane owns pixel hx=l15,
    //      channels nh*16+q*4+{0..3}, rows wp*4+im ----
    {
        f32x4 b2v = *(const f32x4*)&gB2[unit * 32 + nh * 16 + q * 4];
        int gx = ox0 - 2 + l15;
        bool okx = (gx >= 0 && gx < W);
#pragma unroll
        for (int im = 0; im < 4; ++im) {
            int hy = wp * 4 + im;
            int gy = oy0 - 2 + hy;
            bool ok = okx && (gy >= 0 && gy < H);
            float v0 = fmaxf(acc2[im][0] + b2v[0], 0.f);
            float v1 = fmaxf(acc2[im][1] + b2v[1], 0.f);
            float v2 = fmaxf(acc2[im][2] + b2v[2], 0.f);
            float v3 = fmaxf(acc2[im][3] + b2v[3], 0.f);
            unsigned int w0 = pk_bf16(v0, v1);
            unsigned int w1 = pk_bf16(v2, v3);
            if (!ok) { w0 = 0u; w1 = 0u; }
            *(u32x2*)&sH2[(nh * 2 + (q >> 1)) * 2064 + (hy * 16 + l15) * 8 + (q & 1) * 4]
                = (u32x2){w0, w1};
        }
    }
    __syncthreads();

    // ---- phase 3: conv3, tap-outer; mt = wv + 8*jm (wv0: 2 tiles) ----
    float b3 = gB3[unit];
    const int nm = (wv == 0) ? 2 : 1;
    int oyj[2], oxj[2];
#pragma unroll
    for (int jm = 0; jm < 2; ++jm) {
        int p = (wv + 8 * jm) * 16 + l15;            // 0..143 valid range
        oyj[jm] = (p * 683) >> 13;
        oxj[jm] = p - 12 * oyj[jm];
    }
    f32x4 acc3[2];
#pragma unroll
    for (int jm = 0; jm < 2; ++jm) acc3[jm] = (f32x4){0.f, 0.f, 0.f, 0.f};

#pragma unroll 1
    for (int tap = 0; tap < 25; ++tap) {
        int dy = (tap * 13) >> 6, dx = tap - 5 * dy;
        short8 w = *(const short8*)&sW3[tap * 32 + q * 8];
#pragma unroll
        for (int jm = 0; jm < 2; ++jm) {
            if (jm < nm) {
                int h2px = (oyj[jm] + dy) * 16 + oxj[jm] + dx;
                short8 a = *(const short8*)&sH2[q * 2064 + h2px * 8];
                acc3[jm] = MFMA16(a, w, acc3[jm]);
            }
        }
    }
    if (l15 == 0) {
#pragma unroll
        for (int jm = 0; jm < 2; ++jm) {
            if (jm < nm) {
                int mt = wv + 8 * jm;
#pragma unroll
                for (int r = 0; r < 4; ++r) {
                    int pp = mt * 16 + q * 4 + r;
                    int oy = (pp * 683) >> 13, ox = pp - 12 * oy;
                    int gy = oy0 + oy, gx = ox0 + ox;
                    if (gy < H && gx < W) {
                        size_t o = (size_t)b * outW * outH + (size_t)(gy * s2 + ppy) * outW + (gx * s2 + ppx);
                        out[o] = acc3[jm][r] + b3;
                    }
                }
            }
        }
    }
}

// ---------------------------------------------------------------------------
// MSF input: up4(out_x2) + up2(out_x4) + out_x8 (bilinear, half-pixel, clamped)
// ---------------------------------------------------------------------------
__device__ __forceinline__ void ax_w(int i, float inv_s, int n, int& i0, int& i1, float& w1) {
    float c  = (i + 0.5f) * inv_s - 0.5f;
    float fl = floorf(c);
    w1 = c - fl;
    int ii = (int)fl;
    i0 = ii < 0 ? 0 : ii;
    i1 = (ii + 1 >= n) ? (n - 1) : (ii + 1);
}

__global__ __launch_bounds__(256) void msf_in_kernel(
    const float* __restrict__ f2, const float* __restrict__ f4,
    const float* __restrict__ f8, float* __restrict__ dst)
{
    int idx = blockIdx.x * 256 + threadIdx.x;   // 4*512*512
    int x = idx & 511;
    int y = (idx >> 9) & 511;
    int b = idx >> 18;

    int y0, y1, x0, x1;
    float wy, wx;

    ax_w(y, 0.25f, 128, y0, y1, wy);
    ax_w(x, 0.25f, 128, x0, x1, wx);
    const float* p2 = f2 + (size_t)b * 16384;
    float v4 = (1.f - wy) * ((1.f - wx) * p2[y0 * 128 + x0] + wx * p2[y0 * 128 + x1])
             +        wy  * ((1.f - wx) * p2[y1 * 128 + x0] + wx * p2[y1 * 128 + x1]);

    ax_w(y, 0.5f, 256, y0, y1, wy);
    ax_w(x, 0.5f, 256, x0, x1, wx);
    const float* p4 = f4 + (size_t)b * 65536;
    float v2 = (1.f - wy) * ((1.f - wx) * p4[y0 * 256 + x0] + wx * p4[y0 * 256 + x1])
             +        wy  * ((1.f - wx) * p4[y1 * 256 + x0] + wx * p4[y1 * 256 + x1]);

    dst[idx] = v4 + v2 + f8[idx];
}

// ---------------------------------------------------------------------------
extern "C" void kernel_launch(void* const* d_in, const int* in_sizes, int n_in,
                              void* d_out, int out_size, void* d_ws, size_t ws_size,
                              hipStream_t stream)
{
    (void)in_sizes; (void)n_in; (void)out_size; (void)ws_size;

    const float* image = (const float*)d_in[0];
    const float* W1    = (const float*)d_in[1];
    const float* B1    = (const float*)d_in[2];
    const float* W2    = (const float*)d_in[3];
    const float* B2    = (const float*)d_in[4];
    const float* W3    = (const float*)d_in[5];
    const float* B3    = (const float*)d_in[6];

    float* out = (float*)d_out;
    float* o2 = out;                 // (4,1,128,128)
    float* o4 = out + 65536;         // (4,1,256,256)
    float* o8 = out + 327680;        // (4,1,512,512)
    float* om = out + 1376256;       // msf (4,1,512,512)

    float*    fm  = (float*)d_ws;                              // 4 MB
    ushort_t* w1t = (ushort_t*)((char*)d_ws + 4194304);        // 79872 u16
    ushort_t* w2t = (ushort_t*)((char*)d_ws + 4354048);        // 665600 u16
    ushort_t* w3t = (ushort_t*)((char*)d_ws + 5685248);        // 10400 u16

    prep_weights<<<2600, 256, 0, stream>>>(W1, W2, W3, w1t, w2t, w3t);

    srcnn_mfma<<<dim3(6, 6, 16), 512, 0, stream>>>(
        image, 64, 64, w1t, w2t, w3t, B1, B2, B3, 0, o2, 2);
    srcnn_mfma<<<dim3(11, 11, 16), 512, 0, stream>>>(
        o2, 128, 128, w1t, w2t, w3t, B1, B2, B3, 4, o4, 2);
    srcnn_mfma<<<dim3(22, 22, 16), 512, 0, stream>>>(
        o4, 256, 256, w1t, w2t, w3t, B1, B2, B3, 8, o8, 2);
    msf_in_kernel<<<4096, 256, 0, stream>>>(o2, o4, o8, fm);
    srcnn_mfma<<<dim3(43, 43, 4), 512, 0, stream>>>(
        fm, 512, 512, w1t, w2t, w3t, B1, B2, B3, 12, om, 1);
}

// Round 22
// 687.239 us; speedup vs baseline: 1.1997x; 1.1997x over previous
//
#include <hip/hip_runtime.h>

// DSDMSR_x8: 13-unit SRCNN cascade, fp32 I/O, bf16 MFMA compute.
// Per 12x12 output tile (256 thr / 4 waves, __launch_bounds__(256,2)).
// RULES: (r8) disjoint acc lifetimes; (r11) compile-time reg indices;
// (r12) never cap occupancy below demand.
// R1 (verified r4, 994->847us): operands swapped (weights=A, pixels=B).
// R5 (verified r11, 847->639us): phase-2 n fused; A-frag read once.
// R12 (r13 NULL, kept): phase-1 gather k-permute.
// R14 (verified r16, 637->626us): dx0..3 folded into k (broadcast B-reads).
// R17/r18 (REGRESSED, REVERTED): 8-wave blocks -> barrier idling. Lesson:
// occupancy must come from SMALLER LDS (more 4-wave blocks), not wider blocks.
// R19 (theory: latency-bound at 12 waves/CU): h1 SPLIT into channel halves.
//   loop h=0,1: phase1(ch h*32..h*32+31 -> sH1h 4 planes) -> barrier ->
//               [h==1: stage sW3] phase2 half (c8=h*4..h*4+3 + dx4 c=h,
//               acc2 persists) -> barrier
//   then h2 writeback (sH2 overlays sH1h) -> barrier -> phase 3.
// LDS 52928 -> 27264 B => 4-6 blocks/CU (16-24 waves, was 12). Cost: gather
// runs 2x (+~4%), +3 barriers. Phase-1 per-channel sum order identical;
// phase-2 acc2 order: c8 0..3, dx4c0, c8 4..7, dx4c1 (ULP-level reorder).
// R19-resubmit-2 (r20, r21 broker timeouts; unchanged).
// Spill canary: WRITE_SIZE ~5 MB. VGPR canary: <=128 (else occupancy stuck).

typedef unsigned short ushort_t;
typedef __attribute__((ext_vector_type(8))) short short8;   // 8 bf16
typedef __attribute__((ext_vector_type(4))) float f32x4;
typedef __attribute__((ext_vector_type(2))) unsigned int u32x2;

__device__ __forceinline__ float us2f(ushort_t u) { return __uint_as_float(((unsigned int)u) << 16); }
__device__ __forceinline__ ushort_t f2us(float f) {
    unsigned int x = __float_as_uint(f);
    return (ushort_t)((x + 0x7fffu + ((x >> 16) & 1u)) >> 16);
}
// pack two f32 -> two bf16 (RNE), one VOP3
__device__ __forceinline__ unsigned int pk_bf16(float lo, float hi) {
    unsigned int r;
    asm("v_cvt_pk_bf16_f32 %0, %1, %2" : "=v"(r) : "v"(lo), "v"(hi));
    return r;
}

#define MFMA16(a, b, c) __builtin_amdgcn_mfma_f32_16x16x32_bf16((a), (b), (c), 0, 0, 0)

// ---------------------------------------------------------------------------
// Weight prep (unchanged from r14):
//  w1t [u][kc3][cig4][ch64][8]  (tap = kc*32 + e*4 + cig, zero for tap>=81)
//  w2t: main [u][c8][dy][q=dx][co][e] then dx4 [u][c][dy][cig][co][e]
//  w3t [u][tap25][ci32]
// ---------------------------------------------------------------------------
__global__ __launch_bounds__(256) void prep_weights(
    const float* __restrict__ W1, const float* __restrict__ W2, const float* __restrict__ W3,
    ushort_t* __restrict__ w1t, ushort_t* __restrict__ w2t, ushort_t* __restrict__ w3t)
{
    int i = blockIdx.x * 256 + threadIdx.x;
    if (i < 13 * 3 * 4 * 64 * 8) {           // 79872
        int e = i & 7, ch = (i >> 3) & 63, cig = (i >> 9) & 3;
        int r = i >> 11;                     // u*3 + kc
        int kc = r % 3, u = r / 3;
        int tap = kc * 32 + e * 4 + cig;     // r12 k-permute
        w1t[i] = (tap < 81) ? f2us(W1[(u * 64 + ch) * 81 + tap]) : (ushort_t)0;
    }
    if (i < 532480) {                        // main: [u][c8][dy][q][co][e]
        int e = i & 7, co = (i >> 3) & 31, qq = (i >> 8) & 3;
        int b = i >> 10;                     // (u*8 + c8)*5 + dy
        int dy = b % 5, tt = b / 5;
        int c8 = tt % 8, u = tt / 8;
        int ci = c8 * 8 + e;
        int tap = dy * 5 + qq;               // dx = q
        w2t[i] = f2us(W2[((u * 32 + co) * 64 + ci) * 25 + tap]);
    }
    if (i < 133120) {                        // dx4: [u][c][dy][cig][co][e]
        int e = i & 7, co = (i >> 3) & 31, cig = (i >> 8) & 3;
        int b = i >> 10;                     // (u*2 + c)*5 + dy
        int dy = b % 5, s = b / 5;
        int c = s % 2, u = s / 2;
        int ci = c * 32 + cig * 8 + e;
        int tap = dy * 5 + 4;
        w2t[532480 + i] = f2us(W2[((u * 32 + co) * 64 + ci) * 25 + tap]);
    }
    if (i < 13 * 25 * 32) {                  // 10400
        int ci = i & 31, r = i >> 5;
        int tap = r % 25, u = r / 25;
        w3t[i] = f2us(W3[(u * 32 + ci) * 25 + tap]);
    }
}

// ---------------------------------------------------------------------------
__global__ __launch_bounds__(256, 2) void srcnn_mfma(
    const float* __restrict__ in, int H, int W,
    const ushort_t* __restrict__ w1t, const ushort_t* __restrict__ w2t,
    const ushort_t* __restrict__ w3t,
    const float* __restrict__ gB1, const float* __restrict__ gB2,
    const float* __restrict__ gB3,
    int unitBase, float* __restrict__ out, int s2)
{
    __shared__ __align__(16) char smem[27264];
    ushort_t* sH1h = (ushort_t*)smem;             // 4 planes x 3208 shorts = 25664 B
    ushort_t* sInU = (ushort_t*)(smem + 25664);   // 784 bf16 (live through 1b)
    ushort_t* sW3  = (ushort_t*)(smem + 25664);   // 800 u16 (overlays sInU after 1b)
    ushort_t* sH2  = (ushort_t*)smem;             // 4 x 2064 shorts (after 2b)

    const int t = threadIdx.x, lane = t & 63, wv = t >> 6;
    const int q = lane >> 4, l15 = lane & 15;
    const int z = blockIdx.z;
    const int k4 = (s2 == 2) ? (z >> 2) : 0;
    const int b  = (s2 == 2) ? (z & 3)  : z;
    const int unit = unitBase + k4;
    const int ppx = k4 & 1, ppy = k4 >> 1;
    const int ox0 = blockIdx.x * 12, oy0 = blockIdx.y * 12;
    const int outW = W * s2;
    const int outH = H * s2;
    const float* inb = in + (size_t)b * H * W;

    const char* w2m_u = (const char*)w2t + (size_t)unit * 81920;
    const char* w2x_u = (const char*)w2t + 1064960 + (size_t)unit * 20480;

    // load a 10-frag weight set [n*5+dy] for block blk from region base
    auto loadW = [&](short8* buf, const char* base, int blk) {
        const char* g = base + (size_t)blk * 10240 + q * 512 + l15 * 16;
#pragma unroll
        for (int dy = 0; dy < 5; ++dy) {
            buf[dy]     = *(const short8*)(g + dy * 2048);
            buf[5 + dy] = *(const short8*)(g + dy * 2048 + 256);
        }
    };

    // stage input 28x28 (origin -8, zero-padded) as bf16
    for (int idx = t; idx < 784; idx += 256) {
        int y = idx / 28, x = idx - 28 * y;
        int gy = oy0 - 8 + y, gx = ox0 - 8 + x;
        sInU[idx] = (gy >= 0 && gy < H && gx >= 0 && gx < W)
                    ? f2us(inb[(size_t)gy * W + gx]) : (ushort_t)0;
    }
    __syncthreads();

    const ushort_t* w1u = w1t + (size_t)unit * (3 * 4 * 64 * 8);

    // acc2 persists across both halves
    f32x4 acc2[4][2];
#pragma unroll
    for (int i = 0; i < 4; ++i) { acc2[i][0] = (f32x4){0.f,0.f,0.f,0.f}; acc2[i][1] = (f32x4){0.f,0.f,0.f,0.f}; }

#pragma unroll 1
    for (int h = 0; h < 2; ++h) {
        // ---- phase 1 half h: conv1 channels h*32..h*32+31 -> sH1h ----
        {
            f32x4 bias4[2];
#pragma unroll
            for (int n = 0; n < 2; ++n)
                bias4[n] = *(const f32x4*)&gB1[unit * 64 + (h * 2 + n) * 16 + q * 4];

#pragma unroll 1
            for (int ms = 0; ms < 2; ++ms) {
                const int mbase = ms * 16;
                const int nim = ms ? 3 : 4;
                f32x4 acc1h[4][2];
#pragma unroll
                for (int i = 0; i < 4; ++i) {
                    acc1h[i][0] = (f32x4){0.f,0.f,0.f,0.f};
                    acc1h[i][1] = (f32x4){0.f,0.f,0.f,0.f};
                }

#pragma unroll 1
                for (int kc = 0; kc < 3; ++kc) {
                    short8 bh[2];
#pragma unroll
                    for (int n = 0; n < 2; ++n)
                        bh[n] = *(const short8*)&w1u[((kc * 4 + q) * 64 + (h * 2 + n) * 16 + l15) * 8];
                    int toff8[8];
#pragma unroll
                    for (int j = 0; j < 8; ++j) {
                        int T = kc * 32 + j * 4 + q;
                        int ty = (T * 57) >> 9;
                        int o  = ty * 28 + (T - 9 * ty);
                        toff8[j] = (T < 81) ? o : 0;
                    }
#pragma unroll
                    for (int im = 0; im < 4; ++im) {
                        if (im < nim) {
                            int m = mbase + wv + im * 4;
                            if (m < 25) {
                                int px = m * 16 + l15;        // 0..399
                                int py1 = (px * 205) >> 12;
                                int base = py1 * 28 + (px - 20 * py1);
                                union { short8 v; ushort_t u[8]; } a;
#pragma unroll
                                for (int j = 0; j < 8; ++j)
                                    a.u[j] = sInU[base + toff8[j]];
#pragma unroll
                                for (int n = 0; n < 2; ++n)
                                    acc1h[im][n] = MFMA16(bh[n], a.v, acc1h[im][n]);
                            }
                        }
                    }
                }

                // writeback to LOCAL planes n*2+(q>>1) (n local 0..1)
#pragma unroll
                for (int im = 0; im < 4; ++im) {
                    if (im < nim) {
                        int m = mbase + wv + im * 4;
                        if (m < 25) {
                            int px = m * 16 + l15;
                            int py1 = (px * 205) >> 12;
                            int px1 = px - 20 * py1;
                            int gy = oy0 - 4 + py1, gx = ox0 - 4 + px1;
                            bool ok = (gy >= 0 && gy < H && gx >= 0 && gx < W);
#pragma unroll
                            for (int n = 0; n < 2; ++n) {
                                float v0 = fmaxf(acc1h[im][n][0] + bias4[n][0], 0.f);
                                float v1 = fmaxf(acc1h[im][n][1] + bias4[n][1], 0.f);
                                float v2 = fmaxf(acc1h[im][n][2] + bias4[n][2], 0.f);
                                float v3 = fmaxf(acc1h[im][n][3] + bias4[n][3], 0.f);
                                unsigned int w0 = pk_bf16(v0, v1);
                                unsigned int w1 = pk_bf16(v2, v3);
                                if (!ok) { w0 = 0u; w1 = 0u; }
                                *(u32x2*)&sH1h[(n * 2 + (q >> 1)) * 3208 + px * 8 + (q & 1) * 4]
                                    = (u32x2){w0, w1};
                            }
                        }
                    }
                }
            }
        }
        __syncthreads();   // half-h h1 written; (h==1: all sInU reads done)

        // stage w3 after sInU is dead (start of second phase-2 region)
        if (h == 1) {
            const ushort_t* w3u = w3t + unit * 800;
            for (int i = t; i < 800; i += 256) sW3[i] = w3u[i];
        }

        // ---- phase 2 half h: c8 = h*4 + 0..3 (main) + dx4 c=h ----
        {
            short8 Wa[10], Wb[10];
            loadW(Wa, w2m_u, h * 4);
#pragma unroll
            for (int c8l = 0; c8l < 4; ++c8l) {
                const short8* cw = (c8l & 1) ? Wb : Wa;   // compile-time
                short8*       nw = (c8l & 1) ? Wa : Wb;
                if (c8l < 3) loadW(nw, w2m_u, h * 4 + c8l + 1);
                else         loadW(nw, w2x_u, h);         // prefetch dx4 half-h
                const ushort_t* bpl = &sH1h[c8l * 3208];
#pragma unroll
                for (int rel = 0; rel < 8; ++rel) {
                    int row = wv * 4 + rel;
                    short8 bf = *(const short8*)&bpl[(row * 20 + l15 + q) * 8];
                    const int dylo = rel - 3 < 0 ? 0 : rel - 3;
                    const int dyhi = rel < 4 ? rel : 4;
#pragma unroll
                    for (int dy = 0; dy < 5; ++dy) {
                        if (dy >= dylo && dy <= dyhi) {
                            int im = rel - dy;
                            acc2[im][0] = MFMA16(cw[dy],     bf, acc2[im][0]);
                            acc2[im][1] = MFMA16(cw[5 + dy], bf, acc2[im][1]);
                        }
                    }
                }
            }
            // dx4 leg for this half: weights in Wa (prefetched at c8l=3)
            {
                const short8* cw = Wa;
                const ushort_t* base = &sH1h[q * 3208];   // local plane q
#pragma unroll
                for (int rel = 0; rel < 8; ++rel) {
                    int row = wv * 4 + rel;
                    short8 bf = *(const short8*)&base[(row * 20 + l15 + 4) * 8];
                    const int dylo = rel - 3 < 0 ? 0 : rel - 3;
                    const int dyhi = rel < 4 ? rel : 4;
#pragma unroll
                    for (int dy = 0; dy < 5; ++dy) {
                        if (dy >= dylo && dy <= dyhi) {
                            int im = rel - dy;
                            acc2[im][0] = MFMA16(cw[dy],     bf, acc2[im][0]);
                            acc2[im][1] = MFMA16(cw[5 + dy], bf, acc2[im][1]);
                        }
                    }
                }
            }
        }
        __syncthreads();   // half-h sH1h reads done (h==0: before 1b overwrites;
                           // h==1: before sH2 overwrites). sW3 visible too.
    }

    // ---- h2 writeback: lane owns pixel hx=l15, channels n*16+q*4+{0..3} ----
    {
        f32x4 b2v[2];
#pragma unroll
        for (int n = 0; n < 2; ++n)
            b2v[n] = *(const f32x4*)&gB2[unit * 32 + n * 16 + q * 4];
        int gx = ox0 - 2 + l15;
        bool okx = (gx >= 0 && gx < W);
#pragma unroll
        for (int im = 0; im < 4; ++im) {
            int hy = wv * 4 + im;
            int gy = oy0 - 2 + hy;
            bool ok = okx && (gy >= 0 && gy < H);
#pragma unroll
            for (int n = 0; n < 2; ++n) {
                float v0 = fmaxf(acc2[im][n][0] + b2v[n][0], 0.f);
                float v1 = fmaxf(acc2[im][n][1] + b2v[n][1], 0.f);
                float v2 = fmaxf(acc2[im][n][2] + b2v[n][2], 0.f);
                float v3 = fmaxf(acc2[im][n][3] + b2v[n][3], 0.f);
                unsigned int w0 = pk_bf16(v0, v1);
                unsigned int w1 = pk_bf16(v2, v3);
                if (!ok) { w0 = 0u; w1 = 0u; }
                *(u32x2*)&sH2[(n * 2 + (q >> 1)) * 2064 + (hy * 16 + l15) * 8 + (q & 1) * 4]
                    = (u32x2){w0, w1};
            }
        }
    }
    __syncthreads();

    // ---- phase 3: conv3, tap-outer, w-frag hoisted; acc3 12 AGPR static ----
    float b3 = gB3[unit];
    const int nm = (wv == 0) ? 3 : 2;
    int oyj[3], oxj[3];
#pragma unroll
    for (int jm = 0; jm < 3; ++jm) {
        int p = (wv + 4 * jm) * 16 + l15;            // 0..143 valid range
        oyj[jm] = (p * 683) >> 13;
        oxj[jm] = p - 12 * oyj[jm];
    }
    f32x4 acc3[3];
#pragma unroll
    for (int jm = 0; jm < 3; ++jm) acc3[jm] = (f32x4){0.f, 0.f, 0.f, 0.f};

#pragma unroll 1
    for (int tap = 0; tap < 25; ++tap) {
        int dy = (tap * 13) >> 6, dx = tap - 5 * dy;
        short8 w = *(const short8*)&sW3[tap * 32 + q * 8];
#pragma unroll
        for (int jm = 0; jm < 3; ++jm) {
            if (jm < nm) {
                int h2px = (oyj[jm] + dy) * 16 + oxj[jm] + dx;
                short8 a = *(const short8*)&sH2[q * 2064 + h2px * 8];
                acc3[jm] = MFMA16(a, w, acc3[jm]);
            }
        }
    }
    if (l15 == 0) {
#pragma unroll
        for (int jm = 0; jm < 3; ++jm) {
            if (jm < nm) {
                int mt = wv + 4 * jm;
#pragma unroll
                for (int r = 0; r < 4; ++r) {
                    int pp = mt * 16 + q * 4 + r;
                    int oy = (pp * 683) >> 13, ox = pp - 12 * oy;
                    int gy = oy0 + oy, gx = ox0 + ox;
                    if (gy < H && gx < W) {
                        size_t o = (size_t)b * outW * outH + (size_t)(gy * s2 + ppy) * outW + (gx * s2 + ppx);
                        out[o] = acc3[jm][r] + b3;
                    }
                }
            }
        }
    }
}

// ---------------------------------------------------------------------------
// MSF input: up4(out_x2) + up2(out_x4) + out_x8 (bilinear, half-pixel, clamped)
// ---------------------------------------------------------------------------
__device__ __forceinline__ void ax_w(int i, float inv_s, int n, int& i0, int& i1, float& w1) {
    float c  = (i + 0.5f) * inv_s - 0.5f;
    float fl = floorf(c);
    w1 = c - fl;
    int ii = (int)fl;
    i0 = ii < 0 ? 0 : ii;
    i1 = (ii + 1 >= n) ? (n - 1) : (ii + 1);
}

__global__ __launch_bounds__(256) void msf_in_kernel(
    const float* __restrict__ f2, const float* __restrict__ f4,
    const float* __restrict__ f8, float* __restrict__ dst)
{
    int idx = blockIdx.x * 256 + threadIdx.x;   // 4*512*512
    int x = idx & 511;
    int y = (idx >> 9) & 511;
    int b = idx >> 18;

    int y0, y1, x0, x1;
    float wy, wx;

    ax_w(y, 0.25f, 128, y0, y1, wy);
    ax_w(x, 0.25f, 128, x0, x1, wx);
    const float* p2 = f2 + (size_t)b * 16384;
    float v4 = (1.f - wy) * ((1.f - wx) * p2[y0 * 128 + x0] + wx * p2[y0 * 128 + x1])
             +        wy  * ((1.f - wx) * p2[y1 * 128 + x0] + wx * p2[y1 * 128 + x1]);

    ax_w(y, 0.5f, 256, y0, y1, wy);
    ax_w(x, 0.5f, 256, x0, x1, wx);
    const float* p4 = f4 + (size_t)b * 65536;
    float v2 = (1.f - wy) * ((1.f - wx) * p4[y0 * 256 + x0] + wx * p4[y0 * 256 + x1])
             +        wy  * ((1.f - wx) * p4[y1 * 256 + x0] + wx * p4[y1 * 256 + x1]);

    dst[idx] = v4 + v2 + f8[idx];
}

// ---------------------------------------------------------------------------
extern "C" void kernel_launch(void* const* d_in, const int* in_sizes, int n_in,
                              void* d_out, int out_size, void* d_ws, size_t ws_size,
                              hipStream_t stream)
{
    (void)in_sizes; (void)n_in; (void)out_size; (void)ws_size;

    const float* image = (const float*)d_in[0];
    const float* W1    = (const float*)d_in[1];
    const float* B1    = (const float*)d_in[2];
    const float* W2    = (const float*)d_in[3];
    const float* B2    = (const float*)d_in[4];
    const float* W3    = (const float*)d_in[5];
    const float* B3    = (const float*)d_in[6];

    float* out = (float*)d_out;
    float* o2 = out;                 // (4,1,128,128)
    float* o4 = out + 65536;         // (4,1,256,256)
    float* o8 = out + 327680;        // (4,1,512,512)
    float* om = out + 1376256;       // msf (4,1,512,512)

    float*    fm  = (float*)d_ws;                              // 4 MB
    ushort_t* w1t = (ushort_t*)((char*)d_ws + 4194304);        // 79872 u16
    ushort_t* w2t = (ushort_t*)((char*)d_ws + 4354048);        // 665600 u16
    ushort_t* w3t = (ushort_t*)((char*)d_ws + 5685248);        // 10400 u16

    prep_weights<<<2600, 256, 0, stream>>>(W1, W2, W3, w1t, w2t, w3t);

    srcnn_mfma<<<dim3(6, 6, 16), 256, 0, stream>>>(
        image, 64, 64, w1t, w2t, w3t, B1, B2, B3, 0, o2, 2);
    srcnn_mfma<<<dim3(11, 11, 16), 256, 0, stream>>>(
        o2, 128, 128, w1t, w2t, w3t, B1, B2, B3, 4, o4, 2);
    srcnn_mfma<<<dim3(22, 22, 16), 256, 0, stream>>>(
        o4, 256, 256, w1t, w2t, w3t, B1, B2, B3, 8, o8, 2);
    msf_in_kernel<<<4096, 256, 0, stream>>>(o2, o4, o8, fm);
    srcnn_mfma<<<dim3(43, 43, 4), 256, 0, stream>>>(
        fm, 512, 512, w1t, w2t, w3t, B1, B2, B3, 12, om, 1);
}